// Round 7
// baseline (5077.764 us; speedup 1.0000x reference)
//
#include <hip/hip_runtime.h>

typedef _Float16 f16x8 __attribute__((ext_vector_type(8)));
typedef float    f32x4 __attribute__((ext_vector_type(4)));
typedef unsigned long long u64;
typedef u64 u64x2 __attribute__((ext_vector_type(2)));

constexpr int BATCH = 1024;
constexpr int HDIM  = 512;
constexpr int TENC  = 512;
constexpr int PRED  = 48;
constexpr int STEPS = TENC + PRED - 1;   // 559 cell steps; loop runs 560 (last = fc only)
constexpr int NGRP  = 32;
constexpr int GBAT  = 32;
constexpr int UBU   = 64;                // units per block (4 waves x 16)
constexpr int HB_OFF = 32768;

// In-band tag: every stored fp16 h value donates its mantissa LSB. Each 4B
// dword (2 fp16) carries tag bits at bit0 (=t&1) and bit16 (=(t>>1)&1), so
// validation needs only per-dword atomicity. h_t lives in buffer t&1 with
// tag t&3; max producer/consumer skew is provably 1 step (every wave needs
// every other wave's slice each step), so 2-bit tag + ping-pong is ABA-safe.
constexpr u64 TAG_MASK = 0x0001000100010001ull;
__device__ __forceinline__ u64 tag_of(int t) {
  return ((u64)(t & 1) | ((u64)((t >> 1) & 1) << 16)) * 0x0000000100000001ull;
}

__global__ void init_kernel(int* wsi) {
  int idx = blockIdx.x * blockDim.x + threadIdx.x;
  int stride = gridDim.x * blockDim.x;
  const int nws = (HB_OFF + BATCH * HDIM * 2) / 4;  // hbuf[0] = h_0 = zeros (tag 00)
  for (int i = idx; i < nws; i += stride) wsi[i] = 0;
}

static __device__ __forceinline__ f16x8 load16_coh(const _Float16* p) {
  f16x8 v;
  asm volatile("global_load_dwordx4 %0, %1, off sc0 sc1"
               : "=v"(v) : "v"((u64)p) : "memory");
  return v;
}

// Pure dataflow: 4 independent waves per block, no __syncthreads, no flags,
// no fences. Each wave: 16 units (full-K weights in regs), A-frags loaded
// directly from LLC in fragment layout (4-stage pipeline), tag-validated.
// fc computed in the same K-loop via an extra MFMA with w_fc as B-row 0
// (frags streamed from LDS, zero rows for lanes lcol!=0).
__global__ __launch_bounds__(256, 1) void lstm_persist(
    const float* __restrict__ x,
    const float* __restrict__ w_ih,
    const float* __restrict__ w_hh,
    const float* __restrict__ b_ih,
    const float* __restrict__ b_hh,
    const float* __restrict__ w_fc,
    const float* __restrict__ b_fc,
    float* __restrict__ out,          // [1024][48] fp32, plain stores only
    _Float16* __restrict__ hbuf)      // [2][1024][512] fp16 ping-pong, tagged
{
  const int bid  = blockIdx.x;
  const int grp  = bid & (NGRP - 1);
  const int ub   = bid >> 5;
  const int tid  = threadIdx.x;
  const int wid  = tid >> 6;
  const int lane = tid & 63;
  const int quad = lane >> 4;
  const int lcol = lane & 15;
  const int b0   = grp * GBAT;
  const int myu  = ub * UBU + wid * 16 + lcol;

  // w_fc fragment source: wz[k] = fp16(w_fc[k]) for k<512; zeros at 512..519
  __shared__ __align__(16) _Float16 wz[520];
  for (int k = tid; k < 512; k += 256) wz[k] = (_Float16)w_fc[k];
  if (tid < 8) wz[512 + tid] = (_Float16)0.f;
  __syncthreads();   // once, outside the step loop

  // ---- full-K weight B-frags (n=lcol, k=kc*32+quad*8+j) ----
  f16x8 wf[4][16];
  float wih[4], bias[4];
#pragma unroll
  for (int nt = 0; nt < 4; ++nt) {
    const int j = nt * HDIM + myu;
    wih[nt]  = w_ih[j];
    bias[nt] = b_ih[j] + b_hh[j];
#pragma unroll
    for (int kc = 0; kc < 16; ++kc) {
      const float* s = w_hh + (size_t)j * HDIM + kc * 32 + quad * 8;
      f16x8 v;
#pragma unroll
      for (int i = 0; i < 8; ++i) v[i] = (_Float16)s[i];
      wf[nt][kc] = v;
    }
  }
  const float bfc = b_fc[0];
  const int zoff = 512;   // zero-frag offset in wz

  float cst[2][4];
#pragma unroll
  for (int mt = 0; mt < 2; ++mt)
#pragma unroll
    for (int r = 0; r < 4; ++r) cst[mt][r] = 0.f;

  for (int t = 0; t <= STEPS; ++t) {          // t==559: fc-only tail
    const _Float16* hcur = hbuf + (size_t)(t & 1) * BATCH * HDIM;
    _Float16*       hnxt = hbuf + (size_t)((t + 1) & 1) * BATCH * HDIM;
    const u64 expect = tag_of(t);
    const bool dec = (t >= TENC);

    // encoder x_t (read-only, normal cached loads; consumed in epilogue)
    float xtv[2][4];
    if (!dec) {
#pragma unroll
      for (int mt = 0; mt < 2; ++mt)
#pragma unroll
        for (int r = 0; r < 4; ++r)
          xtv[mt][r] = x[(size_t)(b0 + mt * 16 + quad * 4 + r) * TENC + t];
    }

    // A-frag row pointers: A[m=lcol(+16mt)][k=kc*32+quad*8+j]
    const _Float16* rp0 = hcur + (size_t)(b0 + lcol) * HDIM + quad * 8;
    const _Float16* rp1 = hcur + (size_t)(b0 + 16 + lcol) * HDIM + quad * 8;

    f32x4 acc[2][4];
#pragma unroll
    for (int mt = 0; mt < 2; ++mt)
#pragma unroll
      for (int nt = 0; nt < 4; ++nt) acc[mt][nt] = (f32x4){0.f, 0.f, 0.f, 0.f};
    f32x4 accF[2];
    accF[0] = (f32x4){0.f, 0.f, 0.f, 0.f};
    accF[1] = (f32x4){0.f, 0.f, 0.f, 0.f};

    // 4-stage pipeline: stage s = kc in [4s,4s+4), 8 chunks (2 mt x 4 kc)
    f16x8 A[2][2][4];

#define LOAD_STAGE(s_, pb_)                                              \
    {                                                                    \
      _Pragma("unroll")                                                  \
      for (int i = 0; i < 4; ++i) {                                      \
        A[pb_][0][i] = load16_coh(rp0 + ((s_) * 4 + i) * 32);            \
        A[pb_][1][i] = load16_coh(rp1 + ((s_) * 4 + i) * 32);            \
      }                                                                  \
    }

#define VALIDATE_STAGE(s_, pb_)                                          \
    {                                                                    \
      for (;;) {                                                         \
        unsigned bad = 0;                                                \
        _Pragma("unroll")                                                \
        for (int i = 0; i < 4; ++i)                                      \
          _Pragma("unroll")                                              \
          for (int mt = 0; mt < 2; ++mt) {                               \
            u64x2 w2 = __builtin_bit_cast(u64x2, A[pb_][mt][i]);         \
            if (((w2[0] & TAG_MASK) != expect) ||                        \
                ((w2[1] & TAG_MASK) != expect))                          \
              bad |= 1u << (i * 2 + mt);                                 \
          }                                                              \
        if (__ballot(bad != 0) == 0ull) break;                          \
        __builtin_amdgcn_s_sleep(2);                                     \
        _Pragma("unroll")                                                \
        for (int i = 0; i < 4; ++i) {                                    \
          if (bad & (1u << (i * 2 + 0)))                                 \
            A[pb_][0][i] = load16_coh(rp0 + ((s_) * 4 + i) * 32);        \
          if (bad & (1u << (i * 2 + 1)))                                 \
            A[pb_][1][i] = load16_coh(rp1 + ((s_) * 4 + i) * 32);        \
        }                                                                \
        asm volatile("s_waitcnt vmcnt(0)" ::: "memory");                 \
      }                                                                  \
    }

    LOAD_STAGE(0, 0);
    asm volatile("s_waitcnt vmcnt(0)" ::: "memory");
    VALIDATE_STAGE(0, 0);

#pragma unroll
    for (int s = 0; s < 4; ++s) {
      const int pb = s & 1;
      if (s < 3) LOAD_STAGE(s + 1, pb ^ 1);   // prefetch next stage
#pragma unroll
      for (int i = 0; i < 4; ++i) {
        const int kc = s * 4 + i;
        const f16x8 a0 = A[pb][0][i];
        const f16x8 a1 = A[pb][1][i];
#pragma unroll
        for (int nt = 0; nt < 4; ++nt) {
          acc[0][nt] = __builtin_amdgcn_mfma_f32_16x16x32_f16(a0, wf[nt][kc], acc[0][nt], 0, 0, 0);
          acc[1][nt] = __builtin_amdgcn_mfma_f32_16x16x32_f16(a1, wf[nt][kc], acc[1][nt], 0, 0, 0);
        }
        if (dec) {   // fc row: B[0][k]=wfc, B[n!=0]=0 (zero-frag broadcast)
          const f16x8 wv = *reinterpret_cast<const f16x8*>(
              &wz[(lcol == 0) ? (kc * 32 + quad * 8) : zoff]);
          accF[0] = __builtin_amdgcn_mfma_f32_16x16x32_f16(a0, wv, accF[0], 0, 0, 0);
          accF[1] = __builtin_amdgcn_mfma_f32_16x16x32_f16(a1, wv, accF[1], 0, 0, 0);
        }
      }
      if (s < 3) {
        asm volatile("s_waitcnt vmcnt(0)" ::: "memory");
        VALIDATE_STAGE(s + 1, pb ^ 1);
      }
    }

    // decode: xt = fc(h_t) broadcast from accF column 0; store preds
    if (dec) {
#pragma unroll
      for (int mt = 0; mt < 2; ++mt)
#pragma unroll
        for (int r = 0; r < 4; ++r)
          xtv[mt][r] = __shfl(accF[mt][r], quad * 16) + bfc;
      if (ub == 0 && wid == 0 && lcol == 0) {
        const int p = t - TENC;
#pragma unroll
        for (int mt = 0; mt < 2; ++mt)
#pragma unroll
          for (int r = 0; r < 4; ++r)
            out[(size_t)(b0 + mt * 16 + quad * 4 + r) * PRED + p] =
                accF[mt][r] + bfc;
      }
    }

    if (t < STEPS) {
      const u64 tagnew = tag_of(t + 1);
#pragma unroll
      for (int mt = 0; mt < 2; ++mt) {
#pragma unroll
        for (int r = 0; r < 4; ++r) {
          const int b = b0 + mt * 16 + quad * 4 + r;
          const float xt = xtv[mt][r];
          const float gi = acc[mt][0][r] + xt * wih[0] + bias[0];
          const float gf = acc[mt][1][r] + xt * wih[1] + bias[1];
          const float gg = acc[mt][2][r] + xt * wih[2] + bias[2];
          const float go = acc[mt][3][r] + xt * wih[3] + bias[3];
          const float si = 1.f / (1.f + __expf(-gi));
          const float sf = 1.f / (1.f + __expf(-gf));
          const float so = 1.f / (1.f + __expf(-go));
          const float tg = 1.f - 2.f / (1.f + __expf(2.f * gg));
          const float cn = sf * cst[mt][r] + si * tg;
          cst[mt][r] = cn;
          const float tc = 1.f - 2.f / (1.f + __expf(2.f * cn));
          const float hn = so * tc;

          // pack 4 adjacent units across lanes -> one tagged 8B atomic store
          const unsigned short hb = __builtin_bit_cast(unsigned short, (_Float16)hn);
          const unsigned v0  = hb;
          const unsigned o0  = (unsigned)__shfl_xor((int)v0, 1);
          const unsigned p01 = (lcol & 1) ? ((v0 << 16) | o0) : ((o0 << 16) | v0);
          const unsigned q   = (unsigned)__shfl_xor((int)p01, 2);
          u64 p4 = (lcol & 2) ? (((u64)p01 << 32) | (u64)q)
                              : (((u64)q << 32) | (u64)p01);
          p4 = (p4 & ~TAG_MASK) | tagnew;     // stamp step tag into LSBs
          if ((lcol & 3) == ((mt * 4 + r) & 3)) {
            _Float16* dst = hnxt + (size_t)b * HDIM + (ub * UBU + wid * 16 + (lcol & ~3));
            __hip_atomic_store((u64*)dst, p4, __ATOMIC_RELAXED, __HIP_MEMORY_SCOPE_AGENT);
          }
        }
      }
    }
  }
#undef LOAD_STAGE
#undef VALIDATE_STAGE
}

extern "C" void kernel_launch(void* const* d_in, const int* in_sizes, int n_in,
                              void* d_out, int out_size, void* d_ws, size_t ws_size,
                              hipStream_t stream) {
  const float* x    = (const float*)d_in[0];
  const float* w_ih = (const float*)d_in[1];
  const float* w_hh = (const float*)d_in[2];
  const float* b_ih = (const float*)d_in[3];
  const float* b_hh = (const float*)d_in[4];
  const float* w_fc = (const float*)d_in[5];
  const float* b_fc = (const float*)d_in[6];
  float* out = (float*)d_out;
  _Float16* hbuf = (_Float16*)((char*)d_ws + HB_OFF);

  hipLaunchKernelGGL(init_kernel, dim3(256), dim3(256), 0, stream, (int*)d_ws);
  hipLaunchKernelGGL(lstm_persist, dim3(NGRP * 8), dim3(256), 0, stream,
                     x, w_ih, w_hh, b_ih, b_hh, w_fc, b_fc, out, hbuf);
}

// Round 8
// 3875.434 us; speedup vs baseline: 1.3102x; 1.3102x over previous
//
#include <hip/hip_runtime.h>

typedef _Float16 f16x8 __attribute__((ext_vector_type(8)));
typedef float    f32x4 __attribute__((ext_vector_type(4)));
typedef unsigned long long u64;
typedef u64 u64x2 __attribute__((ext_vector_type(2)));

constexpr int BATCH = 1024;
constexpr int HDIM  = 512;
constexpr int TENC  = 512;
constexpr int PRED  = 48;
constexpr int STEPS = TENC + PRED - 1;   // 559 cell steps; loop runs 560 (last = fc only)
constexpr int NGRP  = 32;
constexpr int GBAT  = 32;
constexpr int UBU   = 64;                // units per block (4 waves x 16)
constexpr int HB_OFF = 32768;

// In-band tag: each stored fp16 h donates its mantissa LSB; a 4B dword (2
// fp16) carries tag bits at bit0 and bit16. h_t lives in buffer t&1 with tag
// t&3. Skew proof (R7, passed): no block can write buffer t&1 again (h_{t+2})
// until every block has published h_{t+1}, which requires finishing step t.
constexpr u64 TAG_MASK = 0x0001000100010001ull;
__device__ __forceinline__ u64 tag_of(int t) {
  return ((u64)(t & 1) | ((u64)((t >> 1) & 1) << 16)) * 0x0000000100000001ull;
}

__global__ void init_kernel(int* wsi) {
  int idx = blockIdx.x * blockDim.x + threadIdx.x;
  int stride = gridDim.x * blockDim.x;
  const int nws = (HB_OFF + BATCH * HDIM * 2) / 4;  // hbuf[0] = h_0 = 0 (tag 00)
  for (int i = idx; i < nws; i += stride) wsi[i] = 0;
  // hbuf[1] stays 0xAA poison = invalid for every tag -> consumers wait
}

static __device__ __forceinline__ f16x8 load16_coh(const _Float16* p) {
  f16x8 v;
  asm volatile("global_load_dwordx4 %0, %1, off sc0 sc1"
               : "=v"(v) : "v"((u64)p) : "memory");
  return v;
}

// R6 parallel staging + R7 in-band tags. No flags, no fences, no vmcnt
// drains, no atomics. Per step: own 64-unit slice enters LDS from registers
// (ownpack); 7 remote slices = 7 concurrent 16B loads/thread, tag-validated
// en masse, stale chunks reloaded. fc computed per-block via extra MFMA.
__global__ __launch_bounds__(256, 1) void lstm_persist(
    const float* __restrict__ x,
    const float* __restrict__ w_ih,
    const float* __restrict__ w_hh,
    const float* __restrict__ b_ih,
    const float* __restrict__ b_hh,
    const float* __restrict__ w_fc,
    const float* __restrict__ b_fc,
    float* __restrict__ out,          // [1024][48] fp32, plain stores
    _Float16* __restrict__ hbuf)      // [2][1024][512] fp16 ping-pong, tagged
{
  const int bid  = blockIdx.x;
  const int grp  = bid & (NGRP - 1);
  const int ub   = bid >> 5;          // unit-block 0..7
  const int tid  = threadIdx.x;
  const int wid  = tid >> 6;
  const int lane = tid & 63;
  const int quad = lane >> 4;
  const int lcol = lane & 15;
  const int b0   = grp * GBAT;
  const int myu  = ub * UBU + wid * 16 + lcol;

  __shared__ __align__(16) _Float16 hs[GBAT][520];   // staged h_t (33.3 KB)
  __shared__ __align__(16) _Float16 wz[520];         // fp16 w_fc + zero pad

  for (int k = tid; k < 512; k += 256) wz[k] = (_Float16)w_fc[k];
  if (tid < 8) wz[512 + tid] = (_Float16)0.f;

  // ---- full-K weight B-frags (n=lcol, k=kc*32+quad*8+j) ----
  f16x8 wf[4][16];
  float wih[4], bias[4];
#pragma unroll
  for (int nt = 0; nt < 4; ++nt) {
    const int j = nt * HDIM + myu;
    wih[nt]  = w_ih[j];
    bias[nt] = b_ih[j] + b_hh[j];
#pragma unroll
    for (int kc = 0; kc < 16; ++kc) {
      const float* s = w_hh + (size_t)j * HDIM + kc * 32 + quad * 8;
      f16x8 v;
#pragma unroll
      for (int i = 0; i < 8; ++i) v[i] = (_Float16)s[i];
      wf[nt][kc] = v;
    }
  }
  const float bfc = b_fc[0];

  float cst[2][4];
#pragma unroll
  for (int mt = 0; mt < 2; ++mt)
#pragma unroll
    for (int r = 0; r < 4; ++r) cst[mt][r] = 0.f;

  // ownpack[mt]: this lane's 8B pack (4 units, batch row mt*16+quad*4+(lcol&3))
  // of the CURRENT h_t own slice. h_0 = 0 with tag 00 -> packs are 0.
  u64 ownpack[2] = {0ull, 0ull};

  // remote staging geometry: thread covers row=tid>>3 (0..31), 16B chunk
  // c16=tid&7 within each remote 64-unit slice p (p != ub)
  const int srow = tid >> 3;
  const int sc16 = tid & 7;

  for (int t = 0; t <= STEPS; ++t) {
    const _Float16* hcur = hbuf + (size_t)(t & 1) * BATCH * HDIM;
    _Float16*       hnxt = hbuf + (size_t)((t + 1) & 1) * BATCH * HDIM;
    const u64 expect = tag_of(t);
    const bool dec = (t >= TENC);

    __syncthreads();   // all waves done reading hs (prev GEMM)

    // ---- own slice -> LDS directly (no global round trip) ----
#pragma unroll
    for (int mt = 0; mt < 2; ++mt)
      *reinterpret_cast<u64*>(
          &hs[mt * 16 + quad * 4 + (lcol & 3)][ub * UBU + wid * 16 + (lcol & ~3)]) =
          ownpack[mt];

    // ---- encoder x_t (plain cached loads, overlap the staging RT) ----
    float xtv[2][4];
    if (!dec) {
#pragma unroll
      for (int mt = 0; mt < 2; ++mt)
#pragma unroll
        for (int r = 0; r < 4; ++r)
          xtv[mt][r] = x[(size_t)(b0 + mt * 16 + quad * 4 + r) * TENC + t];
    }

    // ---- 7 remote slices: all loads in flight, validate, reload stale ----
    const _Float16* rbase = hcur + (size_t)(b0 + srow) * HDIM + sc16 * 8;
    f16x8 tmp[7];
#pragma unroll
    for (int i = 0; i < 7; ++i) {
      const int p = i + (i >= ub);
      tmp[i] = load16_coh(rbase + p * UBU);
    }
    asm volatile("s_waitcnt vmcnt(0)" ::: "memory");
    {
      unsigned stale = 0x7f;
      for (;;) {
        unsigned ns = 0;
#pragma unroll
        for (int i = 0; i < 7; ++i)
          if (stale & (1u << i)) {
            u64x2 w2 = __builtin_bit_cast(u64x2, tmp[i]);
            if (((w2[0] & TAG_MASK) != expect) || ((w2[1] & TAG_MASK) != expect))
              ns |= 1u << i;
          }
        if (ns == 0) break;
        __builtin_amdgcn_s_sleep(1);
#pragma unroll
        for (int i = 0; i < 7; ++i)
          if (ns & (1u << i)) {
            const int p = i + (i >= ub);
            tmp[i] = load16_coh(rbase + p * UBU);
          }
        asm volatile("s_waitcnt vmcnt(0)" ::: "memory");
        stale = ns;
      }
    }
#pragma unroll
    for (int i = 0; i < 7; ++i) {
      const int p = i + (i >= ub);
      *reinterpret_cast<f16x8*>(&hs[srow][p * UBU + sc16 * 8]) = tmp[i];
    }
    __syncthreads();   // full h_t staged

    // ---- GEMM (+fc row in decode) from LDS ----
    f32x4 acc[2][4];
#pragma unroll
    for (int mt = 0; mt < 2; ++mt)
#pragma unroll
      for (int nt = 0; nt < 4; ++nt) acc[mt][nt] = (f32x4){0.f, 0.f, 0.f, 0.f};
    f32x4 accF[2];
    accF[0] = (f32x4){0.f, 0.f, 0.f, 0.f};
    accF[1] = (f32x4){0.f, 0.f, 0.f, 0.f};

#pragma unroll
    for (int kc = 0; kc < 16; ++kc) {
      const f16x8 a0 = *reinterpret_cast<const f16x8*>(&hs[lcol][kc * 32 + quad * 8]);
      const f16x8 a1 = *reinterpret_cast<const f16x8*>(&hs[16 + lcol][kc * 32 + quad * 8]);
#pragma unroll
      for (int nt = 0; nt < 4; ++nt) {
        acc[0][nt] = __builtin_amdgcn_mfma_f32_16x16x32_f16(a0, wf[nt][kc], acc[0][nt], 0, 0, 0);
        acc[1][nt] = __builtin_amdgcn_mfma_f32_16x16x32_f16(a1, wf[nt][kc], acc[1][nt], 0, 0, 0);
      }
      if (dec) {   // fc: B row 0 = w_fc, rows 1..15 = 0 (zero-pad broadcast)
        const f16x8 wv = *reinterpret_cast<const f16x8*>(
            &wz[(lcol == 0) ? (kc * 32 + quad * 8) : 512]);
        accF[0] = __builtin_amdgcn_mfma_f32_16x16x32_f16(a0, wv, accF[0], 0, 0, 0);
        accF[1] = __builtin_amdgcn_mfma_f32_16x16x32_f16(a1, wv, accF[1], 0, 0, 0);
      }
    }

    // ---- decode: xt = fc(h_t) (redundant per block, zero communication) ----
    if (dec) {
#pragma unroll
      for (int mt = 0; mt < 2; ++mt)
#pragma unroll
        for (int r = 0; r < 4; ++r)
          xtv[mt][r] = __shfl(accF[mt][r], quad * 16) + bfc;
      if (ub == 0 && wid == 0 && lcol == 0) {
        const int p = t - TENC;
#pragma unroll
        for (int mt = 0; mt < 2; ++mt)
#pragma unroll
          for (int r = 0; r < 4; ++r)
            out[(size_t)(b0 + mt * 16 + quad * 4 + r) * PRED + p] =
                accF[mt][r] + bfc;
      }
    }

    // ---- cell update + tagged publish (no drain — tags carry the sync) ----
    if (t < STEPS) {
      const u64 tagnew = tag_of(t + 1);
#pragma unroll
      for (int mt = 0; mt < 2; ++mt) {
#pragma unroll
        for (int r = 0; r < 4; ++r) {
          const int b = b0 + mt * 16 + quad * 4 + r;
          const float xt = xtv[mt][r];
          const float gi = acc[mt][0][r] + xt * wih[0] + bias[0];
          const float gf = acc[mt][1][r] + xt * wih[1] + bias[1];
          const float gg = acc[mt][2][r] + xt * wih[2] + bias[2];
          const float go = acc[mt][3][r] + xt * wih[3] + bias[3];
          const float si = 1.f / (1.f + __expf(-gi));
          const float sf = 1.f / (1.f + __expf(-gf));
          const float so = 1.f / (1.f + __expf(-go));
          const float tg = 1.f - 2.f / (1.f + __expf(2.f * gg));
          const float cn = sf * cst[mt][r] + si * tg;
          cst[mt][r] = cn;
          const float tc = 1.f - 2.f / (1.f + __expf(2.f * cn));
          const float hn = so * tc;

          // pack 4 adjacent units across lanes -> 8B tagged pack
          const unsigned short hb = __builtin_bit_cast(unsigned short, (_Float16)hn);
          const unsigned v0  = hb;
          const unsigned o0  = (unsigned)__shfl_xor((int)v0, 1);
          const unsigned p01 = (lcol & 1) ? ((v0 << 16) | o0) : ((o0 << 16) | v0);
          const unsigned q   = (unsigned)__shfl_xor((int)p01, 2);
          u64 p4 = (lcol & 2) ? (((u64)p01 << 32) | (u64)q)
                              : (((u64)q << 32) | (u64)p01);
          p4 = (p4 & ~TAG_MASK) | tagnew;
          if ((lcol & 3) == r) {            // owner lane for (mt, r)
            ownpack[mt] = p4;               // own-slice LDS shortcut next step
            _Float16* dst = hnxt + (size_t)b * HDIM + (ub * UBU + wid * 16 + (lcol & ~3));
            __hip_atomic_store((u64*)dst, p4, __ATOMIC_RELAXED, __HIP_MEMORY_SCOPE_AGENT);
          }
        }
      }
    }
  }
}

extern "C" void kernel_launch(void* const* d_in, const int* in_sizes, int n_in,
                              void* d_out, int out_size, void* d_ws, size_t ws_size,
                              hipStream_t stream) {
  const float* x    = (const float*)d_in[0];
  const float* w_ih = (const float*)d_in[1];
  const float* w_hh = (const float*)d_in[2];
  const float* b_ih = (const float*)d_in[3];
  const float* b_hh = (const float*)d_in[4];
  const float* w_fc = (const float*)d_in[5];
  const float* b_fc = (const float*)d_in[6];
  float* out = (float*)d_out;
  _Float16* hbuf = (_Float16*)((char*)d_ws + HB_OFF);

  hipLaunchKernelGGL(init_kernel, dim3(256), dim3(256), 0, stream, (int*)d_ws);
  hipLaunchKernelGGL(lstm_persist, dim3(NGRP * 8), dim3(256), 0, stream,
                     x, w_ih, w_hh, b_ih, b_hh, w_fc, b_fc, out, hbuf);
}